// Round 7
// baseline (338.043 us; speedup 1.0000x reference)
//
#include <hip/hip_runtime.h>

// Problem constants (from reference setup_inputs)
constexpr int NA = 256;   // N_AGENTS
constexpr int B  = 64;    // BATCH
constexpr int S  = 20;    // SEQ
constexpr int H  = 128;   // HID

constexpr int BLOCKS  = 256;   // 4 blocks per batch (agent quarters); 1 block/CU
constexpr int THREADS = 1024;  // 16 waves
constexpr int REPS    = 8;     // internal repeat: diagnostic to expose the kernel
                               // in rocprof top-5 and separate t_exec from
                               // graph-node overhead. Same work each rep ->
                               // bit-identical output, graph-capture safe.

// R7 = R6 body (full LDS row-staging), repeated 8x INSIDE one dispatch.
// Rationale: marginal cost per extra graph NODE was ~22-24us across R3-R6 and
// insensitive to flight depth / XCD swizzle / LDS staging; cannot tell kernel
// time from inter-node overhead. Internal repeat multiplies only t_exec:
//   dur = OH(193us) + 8*t_exec  -> t_exec resolved; if t_exec~21us the
// dispatch (~170us) finally appears in top-5 WITH counters.
__global__ __launch_bounds__(1024, 1) void social_pool_kernel(
    const float* __restrict__ h,    // (NA, B, S, H)
    const float* __restrict__ p,    // (NA, B, S, 2)
    const float* __restrict__ rptr, // scalar radius
    float* __restrict__ out)        // (NA, B, H)
{
    const int q    = blockIdx.x & 3;   // agent quarter: i in [q*64, q*64+64)
    const int b    = blockIdx.x >> 2;  // batch
    const int tid  = threadIdx.x;
    const int wave = tid >> 6;         // 0..15
    const int lane = tid & 63;

    __shared__ float hrow[NA * H];     // 128 KB: all 256 rows of this batch
    __shared__ float px[NA];
    __shared__ float py[NA];

    for (int rep = 0; rep < REPS; ++rep) {
        // Defeat cross-rep CSE/hoisting: force full re-execution of loads.
        asm volatile("" ::: "memory");

        // Positions (scattered 8B loads, 4 of the 16 waves).
        if (tid < NA) {
            const float2 pj = *(const float2*)(p + (((size_t)(tid * B + b)) * S + (S - 1)) * 2);
            px[tid] = pj.x;
            py[tid] = pj.y;
        }

        // Stage all 256 h_last rows: wave w stages rows {it*16 + w}.
        const size_t jstride = (size_t)B * S * H;
        const size_t hlast   = ((size_t)b * S + (S - 1)) * H;
        #pragma unroll
        for (int it = 0; it < 16; ++it) {
            const int row = it * 16 + wave;
            const float2 v = *(const float2*)(h + (size_t)row * jstride + hlast + 2 * lane);
            *(float2*)(&hrow[row * H + 2 * lane]) = v;
        }
        __syncthreads();

        const float radius = *rptr;
        const int ibase = q * 64 + wave * 4;

        // Each wave handles 4 agents; masks are wave-uniform after ballot.
        #pragma unroll
        for (int a = 0; a < 4; ++a) {
            const int i = ibase + a;
            const float xi = px[i];
            const float yi = py[i];

            unsigned long long m[4];
            #pragma unroll
            for (int k = 0; k < 4; ++k) {
                const int j = (k << 6) + lane;
                const float dx   = __fsub_rn(xi, px[j]);
                const float dy   = __fsub_rn(yi, py[j]);
                const float d2   = __fadd_rn(__fmul_rn(dx, dx), __fmul_rn(dy, dy));
                const float dist = __fsqrt_rn(d2);
                m[k] = __ballot(dist <= radius);
            }
            m[i >> 6] &= ~(1ull << (i & 63));  // exclude self
            const int n = __popcll(m[0]) + __popcll(m[1]) + __popcll(m[2]) + __popcll(m[3]);

            // Gather neighbor rows from LDS, 4 words interleaved.
            float ax = 0.0f, ay = 0.0f;
            while (m[0] | m[1] | m[2] | m[3]) {
                float2 v[4];
                bool got[4];
                #pragma unroll
                for (int k = 0; k < 4; ++k) {
                    got[k] = (m[k] != 0ull);
                    if (got[k]) {
                        const int j = (k << 6) + __builtin_ctzll(m[k]);
                        m[k] &= m[k] - 1ull;
                        v[k] = *(const float2*)(&hrow[j * H + 2 * lane]);
                    }
                }
                #pragma unroll
                for (int k = 0; k < 4; ++k) {
                    if (got[k]) { ax += v[k].x; ay += v[k].y; }
                }
            }

            const float c = (float)(n > 0 ? n : 1);
            float2 o;
            o.x = __fdiv_rn(ax, c);
            o.y = __fdiv_rn(ay, c);
            *(float2*)(out + ((size_t)i * B + b) * H + 2 * lane) = o;
        }

        // Next rep re-writes hrow/px/py (identical values); barrier keeps the
        // re-staging from racing this rep's LDS reads.
        __syncthreads();
    }
}

extern "C" void kernel_launch(void* const* d_in, const int* in_sizes, int n_in,
                              void* d_out, int out_size, void* d_ws, size_t ws_size,
                              hipStream_t stream) {
    const float* h    = (const float*)d_in[0];
    const float* p    = (const float*)d_in[1];
    const float* rptr = (const float*)d_in[2];
    float* out        = (float*)d_out;

    (void)in_sizes; (void)n_in; (void)out_size; (void)d_ws; (void)ws_size;

    // Single dispatch (internal 8x repeat) -> no graph-node-gap contamination.
    social_pool_kernel<<<dim3(BLOCKS), dim3(THREADS), 0, stream>>>(h, p, rptr, out);
}